// Round 1
// baseline (26651.422 us; speedup 1.0000x reference)
//
#include <hip/hip_runtime.h>
#include <hip/hip_bf16.h>
#include <math.h>

// Problem constants
#define LYRS 4
#define BB   2
#define SS   2048
#define HH   1024
#define NHD  16
#define HDD  64
#define FFN_ 4096
#define BS   (BB*SS)          // 4096 rows
#define EPS_ 1e-5f

// ---------------- LayerNorm: one block (256 thr) per row of H=1024 ----------
__global__ void ln_f32(const float* __restrict__ x, const float* __restrict__ g,
                       const float* __restrict__ b, float* __restrict__ y) {
    const int row = blockIdx.x;
    const int tid = threadIdx.x;           // 256
    const float* xr = x + (size_t)row * HH;

    float v[4];
    float s = 0.f, s2 = 0.f;
#pragma unroll
    for (int i = 0; i < 4; ++i) {
        v[i] = xr[tid + i * 256];
        s  += v[i];
        s2 += v[i] * v[i];
    }
    // wave reduce (64 lanes)
#pragma unroll
    for (int o = 1; o < 64; o <<= 1) {
        s  += __shfl_xor(s,  o);
        s2 += __shfl_xor(s2, o);
    }
    __shared__ float sh[8];
    const int wave = tid >> 6, lane = tid & 63;
    if (lane == 0) { sh[wave] = s; sh[4 + wave] = s2; }
    __syncthreads();
    if (tid == 0) {
        float ts  = sh[0] + sh[1] + sh[2] + sh[3];
        float ts2 = sh[4] + sh[5] + sh[6] + sh[7];
        float mu  = ts * (1.f / HH);
        sh[0] = mu;
        sh[1] = ts2 * (1.f / HH) - mu * mu;   // var
    }
    __syncthreads();
    const float mu   = sh[0];
    const float rstd = rsqrtf(sh[1] + EPS_);
#pragma unroll
    for (int i = 0; i < 4; ++i) {
        int c = tid + i * 256;
        y[(size_t)row * HH + c] = (v[i] - mu) * rstd * g[c] + b[c];
    }
}

// ---------------- fp32 tiled GEMM: C = A[M,K] @ W[K,N] (+R) (gelu?) --------
#define BM 64
#define BN 64
#define BK 16

template <bool GELU, bool RES>
__global__ void gemm_f32(const float* __restrict__ A, const float* __restrict__ W,
                         const float* __restrict__ R, float* __restrict__ C,
                         int M, int N, int K) {
    __shared__ float As[BK][BM + 1];
    __shared__ float Bs[BK][BN + 1];

    const int tid = threadIdx.x;          // 256
    const int tx = tid & 15, ty = tid >> 4;
    const int row0 = blockIdx.y * BM;
    const int col0 = blockIdx.x * BN;

    float acc[4][4] = {};

    for (int kt = 0; kt < K; kt += BK) {
        // stage A tile: 64 rows x 16 k  (1024 elems, 4 per thread)
#pragma unroll
        for (int it = 0; it < 4; ++it) {
            int li = it * 256 + tid;
            int kl = li & 15, ml = li >> 4;
            As[kl][ml] = A[(size_t)(row0 + ml) * K + kt + kl];
        }
        // stage W tile: 16 k x 64 n (coalesced on n)
#pragma unroll
        for (int it = 0; it < 4; ++it) {
            int li = it * 256 + tid;
            int nl = li & 63, kl = li >> 6;
            Bs[kl][nl] = W[(size_t)(kt + kl) * N + col0 + nl];
        }
        __syncthreads();
#pragma unroll
        for (int kk = 0; kk < BK; ++kk) {
            float a[4], bv[4];
#pragma unroll
            for (int i = 0; i < 4; ++i) a[i]  = As[kk][ty + i * 16];
#pragma unroll
            for (int j = 0; j < 4; ++j) bv[j] = Bs[kk][tx + j * 16];
#pragma unroll
            for (int i = 0; i < 4; ++i)
#pragma unroll
                for (int j = 0; j < 4; ++j)
                    acc[i][j] = fmaf(a[i], bv[j], acc[i][j]);
        }
        __syncthreads();
    }

#pragma unroll
    for (int i = 0; i < 4; ++i) {
        int r = row0 + ty + i * 16;
#pragma unroll
        for (int j = 0; j < 4; ++j) {
            int c = col0 + tx + j * 16;
            float v = acc[i][j];
            if (RES)  v += R[(size_t)r * N + c];
            if (GELU) v = 0.5f * v * (1.0f + erff(v * 0.70710678118654752f));
            C[(size_t)r * N + c] = v;
        }
    }
}

// ---------------- causal flash attention: one wave per query row -----------
// qkv layout: [B, S, 3, NH, HD]  (row stride 3*H = 3072 floats)
__global__ void attn_fa(const float* __restrict__ qkv, float* __restrict__ out) {
    const int lane = threadIdx.x & 63;     // head-dim element
    const int wave = threadIdx.x >> 6;     // 4 waves/block
    const int q    = blockIdx.x * 4 + wave;
    const int h    = blockIdx.y;
    const int b    = blockIdx.z;
    const float scale = 0.125f;            // HD^-0.5

    const size_t rowstride = 3 * HH;
    const size_t base_b = (size_t)b * SS * rowstride;
    const float qv = qkv[base_b + (size_t)q * rowstride + h * HDD + lane];

    float m = -INFINITY, l = 0.f, acc = 0.f;
    for (int j = 0; j <= q; ++j) {
        const size_t kb = base_b + (size_t)j * rowstride + h * HDD + lane;
        float kval = qkv[kb + HH];
        float p = qv * kval;
#pragma unroll
        for (int o = 1; o < 64; o <<= 1) p += __shfl_xor(p, o);
        float s  = p * scale;
        float nm = fmaxf(m, s);
        float alpha = __expf(m - nm);      // 0 on first iter (m=-inf)
        float pe    = __expf(s - nm);
        l = l * alpha + pe;
        float vval = qkv[kb + 2 * HH];
        acc = acc * alpha + pe * vval;
        m = nm;
    }
    out[(size_t)(b * SS + q) * HH + h * HDD + lane] = acc / l;
}

// ---------------------------------------------------------------------------
extern "C" void kernel_launch(void* const* d_in, const int* in_sizes, int n_in,
                              void* d_out, int out_size, void* d_ws, size_t ws_size,
                              hipStream_t stream) {
    const float* hidden = (const float*)d_in[0];
    const float* ln1_g  = (const float*)d_in[1];
    const float* ln1_b  = (const float*)d_in[2];
    const float* Wqkv   = (const float*)d_in[3];
    const float* Wproj  = (const float*)d_in[4];
    const float* ln2_g  = (const float*)d_in[5];
    const float* ln2_b  = (const float*)d_in[6];
    const float* Wfc1   = (const float*)d_in[7];
    const float* Wfc2   = (const float*)d_in[8];
    const float* lnf_g  = (const float*)d_in[9];
    const float* lnf_b  = (const float*)d_in[10];

    float* x = (float*)d_out;              // residual stream lives in d_out
    float* ws    = (float*)d_ws;
    float* hbuf  = ws;                                     //  4M floats
    float* qkvb  = hbuf + (size_t)BS * HH;                 // 12M floats
    float* attnb = qkvb + (size_t)BS * 3 * HH;             //  4M floats
    float* ffnb  = attnb + (size_t)BS * HH;                // 16M floats

    hipMemcpyAsync(x, hidden, (size_t)BS * HH * sizeof(float),
                   hipMemcpyDeviceToDevice, stream);

    for (int lyr = 0; lyr < LYRS; ++lyr) {
        // h = LN1(x)
        ln_f32<<<BS, 256, 0, stream>>>(x, ln1_g + lyr * HH, ln1_b + lyr * HH, hbuf);
        // qkv = h @ Wqkv
        gemm_f32<false, false><<<dim3(3 * HH / BN, BS / BM), 256, 0, stream>>>(
            hbuf, Wqkv + (size_t)lyr * HH * 3 * HH, nullptr, qkvb, BS, 3 * HH, HH);
        // attention
        attn_fa<<<dim3(SS / 4, NHD, BB), 256, 0, stream>>>(qkvb, attnb);
        // x = x + attn @ Wproj
        gemm_f32<false, true><<<dim3(HH / BN, BS / BM), 256, 0, stream>>>(
            attnb, Wproj + (size_t)lyr * HH * HH, x, x, BS, HH, HH);
        // h = LN2(x)
        ln_f32<<<BS, 256, 0, stream>>>(x, ln2_g + lyr * HH, ln2_b + lyr * HH, hbuf);
        // ffn = gelu(h @ Wfc1)
        gemm_f32<true, false><<<dim3(FFN_ / BN, BS / BM), 256, 0, stream>>>(
            hbuf, Wfc1 + (size_t)lyr * HH * FFN_, nullptr, ffnb, BS, FFN_, HH);
        // x = x + ffn @ Wfc2
        gemm_f32<false, true><<<dim3(HH / BN, BS / BM), 256, 0, stream>>>(
            ffnb, Wfc2 + (size_t)lyr * FFN_ * HH, x, x, BS, HH, FFN_);
    }
    // final LN (in-place on d_out)
    ln_f32<<<BS, 256, 0, stream>>>(x, lnf_g, lnf_b, x);
}

// Round 2
// 9884.306 us; speedup vs baseline: 2.6963x; 2.6963x over previous
//
#include <hip/hip_runtime.h>
#include <hip/hip_bf16.h>
#include <math.h>

// Problem constants
#define LYRS 4
#define BB   2
#define SS   2048
#define HH   1024
#define NHD  16
#define HDD  64
#define FFN_ 4096
#define BS   (BB*SS)          // 4096 rows
#define EPS_ 1e-5f

// ---------------- LayerNorm: one block (256 thr) per row of H=1024 ----------
__global__ void ln_f32(const float* __restrict__ x, const float* __restrict__ g,
                       const float* __restrict__ b, float* __restrict__ y) {
    const int row = blockIdx.x;
    const int tid = threadIdx.x;           // 256
    const float* xr = x + (size_t)row * HH;

    float v[4];
    float s = 0.f, s2 = 0.f;
#pragma unroll
    for (int i = 0; i < 4; ++i) {
        v[i] = xr[tid + i * 256];
        s  += v[i];
        s2 += v[i] * v[i];
    }
#pragma unroll
    for (int o = 1; o < 64; o <<= 1) {
        s  += __shfl_xor(s,  o);
        s2 += __shfl_xor(s2, o);
    }
    __shared__ float sh[8];
    const int wave = tid >> 6, lane = tid & 63;
    if (lane == 0) { sh[wave] = s; sh[4 + wave] = s2; }
    __syncthreads();
    if (tid == 0) {
        float ts  = sh[0] + sh[1] + sh[2] + sh[3];
        float ts2 = sh[4] + sh[5] + sh[6] + sh[7];
        float mu  = ts * (1.f / HH);
        sh[0] = mu;
        sh[1] = ts2 * (1.f / HH) - mu * mu;   // var
    }
    __syncthreads();
    const float mu   = sh[0];
    const float rstd = rsqrtf(sh[1] + EPS_);
#pragma unroll
    for (int i = 0; i < 4; ++i) {
        int c = tid + i * 256;
        y[(size_t)row * HH + c] = (v[i] - mu) * rstd * g[c] + b[c];
    }
}

// ---------------- fp32 tiled GEMM: C = A[M,K] @ W[K,N] (+R) (gelu?) --------
#define BM 64
#define BN 64
#define BK 16

template <bool GELU, bool RES>
__global__ void gemm_f32(const float* __restrict__ A, const float* __restrict__ W,
                         const float* __restrict__ R, float* __restrict__ C,
                         int M, int N, int K) {
    __shared__ float As[BK][BM + 1];
    __shared__ float Bs[BK][BN + 1];

    const int tid = threadIdx.x;          // 256
    const int tx = tid & 15, ty = tid >> 4;
    const int row0 = blockIdx.y * BM;
    const int col0 = blockIdx.x * BN;

    float acc[4][4] = {};

    for (int kt = 0; kt < K; kt += BK) {
#pragma unroll
        for (int it = 0; it < 4; ++it) {
            int li = it * 256 + tid;
            int kl = li & 15, ml = li >> 4;
            As[kl][ml] = A[(size_t)(row0 + ml) * K + kt + kl];
        }
#pragma unroll
        for (int it = 0; it < 4; ++it) {
            int li = it * 256 + tid;
            int nl = li & 63, kl = li >> 6;
            Bs[kl][nl] = W[(size_t)(kt + kl) * N + col0 + nl];
        }
        __syncthreads();
#pragma unroll
        for (int kk = 0; kk < BK; ++kk) {
            float a[4], bv[4];
#pragma unroll
            for (int i = 0; i < 4; ++i) a[i]  = As[kk][ty + i * 16];
#pragma unroll
            for (int j = 0; j < 4; ++j) bv[j] = Bs[kk][tx + j * 16];
#pragma unroll
            for (int i = 0; i < 4; ++i)
#pragma unroll
                for (int j = 0; j < 4; ++j)
                    acc[i][j] = fmaf(a[i], bv[j], acc[i][j]);
        }
        __syncthreads();
    }

#pragma unroll
    for (int i = 0; i < 4; ++i) {
        int r = row0 + ty + i * 16;
#pragma unroll
        for (int j = 0; j < 4; ++j) {
            int c = col0 + tx + j * 16;
            float v = acc[i][j];
            if (RES)  v += R[(size_t)r * N + c];
            if (GELU) v = 0.5f * v * (1.0f + erff(v * 0.70710678118654752f));
            C[(size_t)r * N + c] = v;
        }
    }
}

// ---------------- tiled causal flash attention --------------------------------
// one block = 64 queries x 1 head. qkv layout [B,S,3,NH,HD], row stride 3*H.
__global__ __launch_bounds__(256) void attn_fa2(const float* __restrict__ qkv,
                                                float* __restrict__ out) {
    __shared__ float Qs[64][65];   // transposed: Qs[d][q]
    __shared__ float Ks[64][65];   // transposed: Ks[d][k]
    __shared__ float Vs[64][65];   // Vs[k][d]
    __shared__ float Ps[64][65];   // Ps[q][k]

    const int tid = threadIdx.x;
    const int tx = tid & 15, ty = tid >> 4;
    const int qt = blockIdx.x;
    const int h  = blockIdx.y;
    const int b  = blockIdx.z;
    const int q0 = qt * 64;
    const float scale = 0.125f;    // HD^-0.5

    const size_t rowstride = 3 * HH;
    const size_t base = (size_t)b * SS * rowstride + (size_t)h * HDD;

    // load Q tile (transposed)
#pragma unroll
    for (int it = 0; it < 16; ++it) {
        int li = it * 256 + tid;
        int r = li >> 6, c = li & 63;
        Qs[c][r] = qkv[base + (size_t)(q0 + r) * rowstride + c];
    }

    float o[4][4] = {};
    float m_i[4], l_i[4];
#pragma unroll
    for (int i = 0; i < 4; ++i) { m_i[i] = -INFINITY; l_i[i] = 0.f; }

    for (int kt = 0; kt <= qt; ++kt) {
        const int k0 = kt * 64;
        __syncthreads();           // previous PV done before overwriting K/V
#pragma unroll
        for (int it = 0; it < 16; ++it) {
            int li = it * 256 + tid;
            int r = li >> 6, c = li & 63;
            size_t g = base + (size_t)(k0 + r) * rowstride + c;
            Ks[c][r] = qkv[g + HH];        // K
            Vs[r][c] = qkv[g + 2 * HH];    // V
        }
        __syncthreads();

        // scores: S = Q @ K^T  (64x64x64, 4x4/thread)
        float s[4][4] = {};
#pragma unroll 8
        for (int d = 0; d < 64; ++d) {
            float a[4], bv[4];
#pragma unroll
            for (int i = 0; i < 4; ++i) a[i]  = Qs[d][ty + i * 16];
#pragma unroll
            for (int j = 0; j < 4; ++j) bv[j] = Ks[d][tx + j * 16];
#pragma unroll
            for (int i = 0; i < 4; ++i)
#pragma unroll
                for (int j = 0; j < 4; ++j)
                    s[i][j] = fmaf(a[i], bv[j], s[i][j]);
        }

        // scale + causal mask (only diagonal tile partial)
#pragma unroll
        for (int i = 0; i < 4; ++i)
#pragma unroll
            for (int j = 0; j < 4; ++j) {
                s[i][j] *= scale;
                if (kt == qt && (k0 + tx + j * 16) > (q0 + ty + i * 16))
                    s[i][j] = -INFINITY;
            }

        // online softmax update
        float alpha[4];
#pragma unroll
        for (int i = 0; i < 4; ++i) {
            float tm = fmaxf(fmaxf(s[i][0], s[i][1]), fmaxf(s[i][2], s[i][3]));
#pragma unroll
            for (int off = 1; off < 16; off <<= 1)
                tm = fmaxf(tm, __shfl_xor(tm, off));
            float mn = fmaxf(m_i[i], tm);
            alpha[i] = __expf(m_i[i] - mn);
            m_i[i] = mn;
            float sum = 0.f;
#pragma unroll
            for (int j = 0; j < 4; ++j) {
                s[i][j] = __expf(s[i][j] - mn);
                sum += s[i][j];
            }
#pragma unroll
            for (int off = 1; off < 16; off <<= 1)
                sum += __shfl_xor(sum, off);
            l_i[i] = l_i[i] * alpha[i] + sum;
        }

        // write P to LDS, rescale O
#pragma unroll
        for (int i = 0; i < 4; ++i)
#pragma unroll
            for (int j = 0; j < 4; ++j) {
                Ps[ty + i * 16][tx + j * 16] = s[i][j];
                o[i][j] *= alpha[i];
            }
        __syncthreads();

        // O += P @ V  (64x64x64)
#pragma unroll 8
        for (int k = 0; k < 64; ++k) {
            float pv[4], vv[4];
#pragma unroll
            for (int i = 0; i < 4; ++i) pv[i] = Ps[ty + i * 16][k];
#pragma unroll
            for (int j = 0; j < 4; ++j) vv[j] = Vs[k][tx + j * 16];
#pragma unroll
            for (int i = 0; i < 4; ++i)
#pragma unroll
                for (int j = 0; j < 4; ++j)
                    o[i][j] = fmaf(pv[i], vv[j], o[i][j]);
        }
    }

    // epilogue: normalize and store
#pragma unroll
    for (int i = 0; i < 4; ++i) {
        float inv_l = 1.f / l_i[i];
#pragma unroll
        for (int j = 0; j < 4; ++j) {
            out[(size_t)(b * SS + q0 + ty + i * 16) * HH + h * HDD + tx + j * 16] =
                o[i][j] * inv_l;
        }
    }
}

// ---------------------------------------------------------------------------
extern "C" void kernel_launch(void* const* d_in, const int* in_sizes, int n_in,
                              void* d_out, int out_size, void* d_ws, size_t ws_size,
                              hipStream_t stream) {
    const float* hidden = (const float*)d_in[0];
    const float* ln1_g  = (const float*)d_in[1];
    const float* ln1_b  = (const float*)d_in[2];
    const float* Wqkv   = (const float*)d_in[3];
    const float* Wproj  = (const float*)d_in[4];
    const float* ln2_g  = (const float*)d_in[5];
    const float* ln2_b  = (const float*)d_in[6];
    const float* Wfc1   = (const float*)d_in[7];
    const float* Wfc2   = (const float*)d_in[8];
    const float* lnf_g  = (const float*)d_in[9];
    const float* lnf_b  = (const float*)d_in[10];

    float* x = (float*)d_out;              // residual stream lives in d_out
    float* ws    = (float*)d_ws;
    float* hbuf  = ws;                                     //  4M floats
    float* qkvb  = hbuf + (size_t)BS * HH;                 // 12M floats
    float* attnb = qkvb + (size_t)BS * 3 * HH;             //  4M floats
    float* ffnb  = attnb + (size_t)BS * HH;                // 16M floats

    hipMemcpyAsync(x, hidden, (size_t)BS * HH * sizeof(float),
                   hipMemcpyDeviceToDevice, stream);

    for (int lyr = 0; lyr < LYRS; ++lyr) {
        ln_f32<<<BS, 256, 0, stream>>>(x, ln1_g + lyr * HH, ln1_b + lyr * HH, hbuf);
        gemm_f32<false, false><<<dim3(3 * HH / BN, BS / BM), 256, 0, stream>>>(
            hbuf, Wqkv + (size_t)lyr * HH * 3 * HH, nullptr, qkvb, BS, 3 * HH, HH);
        attn_fa2<<<dim3(SS / 64, NHD, BB), 256, 0, stream>>>(qkvb, attnb);
        gemm_f32<false, true><<<dim3(HH / BN, BS / BM), 256, 0, stream>>>(
            attnb, Wproj + (size_t)lyr * HH * HH, x, x, BS, HH, HH);
        ln_f32<<<BS, 256, 0, stream>>>(x, ln2_g + lyr * HH, ln2_b + lyr * HH, hbuf);
        gemm_f32<true, false><<<dim3(FFN_ / BN, BS / BM), 256, 0, stream>>>(
            hbuf, Wfc1 + (size_t)lyr * HH * FFN_, nullptr, ffnb, BS, FFN_, HH);
        gemm_f32<false, true><<<dim3(HH / BN, BS / BM), 256, 0, stream>>>(
            ffnb, Wfc2 + (size_t)lyr * FFN_ * HH, x, x, BS, HH, FFN_);
    }
    ln_f32<<<BS, 256, 0, stream>>>(x, lnf_g, lnf_b, x);
}

// Round 3
// 3840.422 us; speedup vs baseline: 6.9397x; 2.5738x over previous
//
#include <hip/hip_runtime.h>
#include <hip/hip_bf16.h>
#include <math.h>

// Problem constants
#define LYRS 4
#define BB   2
#define SS   2048
#define HH   1024
#define NHD  16
#define HDD  64
#define FFN_ 4096
#define BS   (BB*SS)          // 4096 rows
#define EPS_ 1e-5f

typedef __attribute__((ext_vector_type(8))) __bf16 bf16x8;
typedef __attribute__((ext_vector_type(4))) float f32x4;
typedef __attribute__((address_space(1))) void* gas_t;
typedef __attribute__((address_space(3))) void* las_t;

__device__ inline void async16(void* lds, const void* g) {
    __builtin_amdgcn_global_load_lds((gas_t)g, (las_t)lds, 16, 0, 0);
}

__device__ inline void storev(float* p, float v) { *p = v; }
__device__ inline void storev(__hip_bfloat16* p, float v) { *p = __float2bfloat16(v); }

// ---------------- LayerNorm: one block (256 thr) per row of H=1024 ----------
template <typename OutT>
__global__ void ln_k(const float* __restrict__ x, const float* __restrict__ g,
                     const float* __restrict__ b, OutT* __restrict__ y) {
    const int row = blockIdx.x;
    const int tid = threadIdx.x;           // 256
    const float* xr = x + (size_t)row * HH;

    float v[4];
    float s = 0.f, s2 = 0.f;
#pragma unroll
    for (int i = 0; i < 4; ++i) {
        v[i] = xr[tid + i * 256];
        s  += v[i];
        s2 += v[i] * v[i];
    }
#pragma unroll
    for (int o = 1; o < 64; o <<= 1) {
        s  += __shfl_xor(s,  o);
        s2 += __shfl_xor(s2, o);
    }
    __shared__ float sh[8];
    const int wave = tid >> 6, lane = tid & 63;
    if (lane == 0) { sh[wave] = s; sh[4 + wave] = s2; }
    __syncthreads();
    if (tid == 0) {
        float ts  = sh[0] + sh[1] + sh[2] + sh[3];
        float ts2 = sh[4] + sh[5] + sh[6] + sh[7];
        float mu  = ts * (1.f / HH);
        sh[0] = mu;
        sh[1] = ts2 * (1.f / HH) - mu * mu;   // var
    }
    __syncthreads();
    const float mu   = sh[0];
    const float rstd = rsqrtf(sh[1] + EPS_);
#pragma unroll
    for (int i = 0; i < 4; ++i) {
        int c = tid + i * 256;
        storev(&y[(size_t)row * HH + c], (v[i] - mu) * rstd * g[c] + b[c]);
    }
}

// ---------------- transpose + cast: W[K,N] f32 -> WT[N,K] bf16 --------------
__global__ __launch_bounds__(256) void transpose_cast(const float* __restrict__ W,
                                                      __hip_bfloat16* __restrict__ WT,
                                                      int K, int N) {
    __shared__ float t[32][33];
    const int n0 = blockIdx.x * 32, k0 = blockIdx.y * 32;
    const int tx = threadIdx.x & 31, ty8 = threadIdx.x >> 5;   // ty8: 0..7
#pragma unroll
    for (int i = 0; i < 4; ++i) {
        int k = ty8 + i * 8;
        t[k][tx] = W[(size_t)(k0 + k) * N + n0 + tx];
    }
    __syncthreads();
#pragma unroll
    for (int i = 0; i < 4; ++i) {
        int n = ty8 + i * 8;
        WT[(size_t)(n0 + n) * K + k0 + tx] = __float2bfloat16(t[tx][n]);
    }
}

// ---------------- bf16 MFMA GEMM: C = A[M,K] @ BT[N,K]^T (+R)(gelu?) --------
// m97 recipe: 128x128 tile, BK=32, 4 waves, 4x4 16x16x32 MFMAs per wave.
template <bool GELU, bool RES, typename OutT>
__global__ __launch_bounds__(256) void gemm_bf16(
    const __hip_bfloat16* __restrict__ A,    // [M,K] row-major
    const __hip_bfloat16* __restrict__ BT,   // [N,K] row-major (= B^T)
    const float* __restrict__ R,             // residual [M,N] fp32 (or null)
    OutT* __restrict__ C,                    // [M,N]
    int M, int N, int K)
{
    __shared__ unsigned short As[128 * 32];
    __shared__ unsigned short Bs[128 * 32];

    const int tid  = threadIdx.x;
    const int lane = tid & 63;
    const int wv   = tid >> 6;               // 0..3
    const int wy   = wv >> 1, wx = wv & 1;   // 2x2 wave grid (64x64 each)
    const int row0 = blockIdx.y * 128;
    const int col0 = blockIdx.x * 128;
    const int lm   = lane & 15;              // m (A) / n (B) within 16-tile
    const int kq   = lane >> 4;              // k-quad

    const unsigned short* Ag = (const unsigned short*)A;
    const unsigned short* Bg = (const unsigned short*)BT;

    f32x4 acc[4][4] = {};

    for (int k0 = 0; k0 < K; k0 += 32) {
        __syncthreads();
#pragma unroll
        for (int it = 0; it < 2; ++it) {
            int li = it * 256 + tid;         // 0..511, 16B each
            int r = li >> 2, c = (li & 3) << 3;
            async16(&As[li * 8], &Ag[(size_t)(row0 + r) * K + k0 + c]);
            async16(&Bs[li * 8], &Bg[(size_t)(col0 + r) * K + k0 + c]);
        }
        __syncthreads();

        bf16x8 af[4], bfr[4];
#pragma unroll
        for (int i = 0; i < 4; ++i)
            af[i] = *(const bf16x8*)&As[(wy * 64 + i * 16 + lm) * 32 + kq * 8];
#pragma unroll
        for (int j = 0; j < 4; ++j)
            bfr[j] = *(const bf16x8*)&Bs[(wx * 64 + j * 16 + lm) * 32 + kq * 8];
#pragma unroll
        for (int i = 0; i < 4; ++i)
#pragma unroll
            for (int j = 0; j < 4; ++j)
                acc[i][j] = __builtin_amdgcn_mfma_f32_16x16x32_bf16(
                    af[i], bfr[j], acc[i][j], 0, 0, 0);
    }

    // epilogue: C/D mapping col=lane&15, row=kq*4+reg
#pragma unroll
    for (int i = 0; i < 4; ++i) {
#pragma unroll
        for (int j = 0; j < 4; ++j) {
            int gc = col0 + wx * 64 + j * 16 + lm;
#pragma unroll
            for (int r = 0; r < 4; ++r) {
                int gr = row0 + wy * 64 + i * 16 + kq * 4 + r;
                float v = acc[i][j][r];
                if (RES)  v += R[(size_t)gr * N + gc];
                if (GELU) v = 0.5f * v * (1.0f + erff(v * 0.70710678118654752f));
                storev(&C[(size_t)gr * N + gc], v);
            }
        }
    }
}

// ---------------- tiled causal flash attention (bf16 in/out) ---------------
// one block = 64 queries x 1 head. qkv layout [B,S,3,NH,HD], row stride 3*H.
__global__ __launch_bounds__(256) void attn_fa2(const __hip_bfloat16* __restrict__ qkv,
                                                __hip_bfloat16* __restrict__ out) {
    __shared__ float Qs[64][65];   // transposed: Qs[d][q]
    __shared__ float Ks[64][65];   // transposed: Ks[d][k]
    __shared__ float Vs[64][65];   // Vs[k][d]
    __shared__ float Ps[64][65];   // Ps[q][k]

    const int tid = threadIdx.x;
    const int tx = tid & 15, ty = tid >> 4;
    const int qt = blockIdx.x;
    const int h  = blockIdx.y;
    const int b  = blockIdx.z;
    const int q0 = qt * 64;
    const float scale = 0.125f;    // HD^-0.5

    const size_t rowstride = 3 * HH;
    const size_t base = (size_t)b * SS * rowstride + (size_t)h * HDD;

#pragma unroll
    for (int it = 0; it < 16; ++it) {
        int li = it * 256 + tid;
        int r = li >> 6, c = li & 63;
        Qs[c][r] = __bfloat162float(qkv[base + (size_t)(q0 + r) * rowstride + c]);
    }

    float o[4][4] = {};
    float m_i[4], l_i[4];
#pragma unroll
    for (int i = 0; i < 4; ++i) { m_i[i] = -INFINITY; l_i[i] = 0.f; }

    for (int kt = 0; kt <= qt; ++kt) {
        const int k0 = kt * 64;
        __syncthreads();
#pragma unroll
        for (int it = 0; it < 16; ++it) {
            int li = it * 256 + tid;
            int r = li >> 6, c = li & 63;
            size_t g = base + (size_t)(k0 + r) * rowstride + c;
            Ks[c][r] = __bfloat162float(qkv[g + HH]);
            Vs[r][c] = __bfloat162float(qkv[g + 2 * HH]);
        }
        __syncthreads();

        float s[4][4] = {};
#pragma unroll 8
        for (int d = 0; d < 64; ++d) {
            float a[4], bv[4];
#pragma unroll
            for (int i = 0; i < 4; ++i) a[i]  = Qs[d][ty + i * 16];
#pragma unroll
            for (int j = 0; j < 4; ++j) bv[j] = Ks[d][tx + j * 16];
#pragma unroll
            for (int i = 0; i < 4; ++i)
#pragma unroll
                for (int j = 0; j < 4; ++j)
                    s[i][j] = fmaf(a[i], bv[j], s[i][j]);
        }

#pragma unroll
        for (int i = 0; i < 4; ++i)
#pragma unroll
            for (int j = 0; j < 4; ++j) {
                s[i][j] *= scale;
                if (kt == qt && (k0 + tx + j * 16) > (q0 + ty + i * 16))
                    s[i][j] = -INFINITY;
            }

        float alpha[4];
#pragma unroll
        for (int i = 0; i < 4; ++i) {
            float tm = fmaxf(fmaxf(s[i][0], s[i][1]), fmaxf(s[i][2], s[i][3]));
#pragma unroll
            for (int off = 1; off < 16; off <<= 1)
                tm = fmaxf(tm, __shfl_xor(tm, off));
            float mn = fmaxf(m_i[i], tm);
            alpha[i] = __expf(m_i[i] - mn);
            m_i[i] = mn;
            float sum = 0.f;
#pragma unroll
            for (int j = 0; j < 4; ++j) {
                s[i][j] = __expf(s[i][j] - mn);
                sum += s[i][j];
            }
#pragma unroll
            for (int off = 1; off < 16; off <<= 1)
                sum += __shfl_xor(sum, off);
            l_i[i] = l_i[i] * alpha[i] + sum;
        }

#pragma unroll
        for (int i = 0; i < 4; ++i)
#pragma unroll
            for (int j = 0; j < 4; ++j) {
                Ps[ty + i * 16][tx + j * 16] = s[i][j];
                o[i][j] *= alpha[i];
            }
        __syncthreads();

#pragma unroll 8
        for (int k = 0; k < 64; ++k) {
            float pv[4], vv[4];
#pragma unroll
            for (int i = 0; i < 4; ++i) pv[i] = Ps[ty + i * 16][k];
#pragma unroll
            for (int j = 0; j < 4; ++j) vv[j] = Vs[k][tx + j * 16];
#pragma unroll
            for (int i = 0; i < 4; ++i)
#pragma unroll
                for (int j = 0; j < 4; ++j)
                    o[i][j] = fmaf(pv[i], vv[j], o[i][j]);
        }
    }

#pragma unroll
    for (int i = 0; i < 4; ++i) {
        float inv_l = 1.f / l_i[i];
#pragma unroll
        for (int j = 0; j < 4; ++j) {
            out[(size_t)(b * SS + q0 + ty + i * 16) * HH + h * HDD + tx + j * 16] =
                __float2bfloat16(o[i][j] * inv_l);
        }
    }
}

// ---------------------------------------------------------------------------
extern "C" void kernel_launch(void* const* d_in, const int* in_sizes, int n_in,
                              void* d_out, int out_size, void* d_ws, size_t ws_size,
                              hipStream_t stream) {
    const float* hidden = (const float*)d_in[0];
    const float* ln1_g  = (const float*)d_in[1];
    const float* ln1_b  = (const float*)d_in[2];
    const float* Wqkv   = (const float*)d_in[3];
    const float* Wproj  = (const float*)d_in[4];
    const float* ln2_g  = (const float*)d_in[5];
    const float* ln2_b  = (const float*)d_in[6];
    const float* Wfc1   = (const float*)d_in[7];
    const float* Wfc2   = (const float*)d_in[8];
    const float* lnf_g  = (const float*)d_in[9];
    const float* lnf_b  = (const float*)d_in[10];

    float* x = (float*)d_out;              // residual stream (fp32) in d_out

    char* p = (char*)d_ws;
    __hip_bfloat16* hbuf  = (__hip_bfloat16*)p; p += (size_t)BS * HH * 2;        //  8MB
    __hip_bfloat16* qkvb  = (__hip_bfloat16*)p; p += (size_t)BS * 3 * HH * 2;    // 24MB
    __hip_bfloat16* attnb = (__hip_bfloat16*)p; p += (size_t)BS * HH * 2;        //  8MB
    __hip_bfloat16* ffnb  = (__hip_bfloat16*)p; p += (size_t)BS * FFN_ * 2;      // 32MB
    __hip_bfloat16* wqkvT = (__hip_bfloat16*)p; p += (size_t)3 * HH * HH * 2;    //  6MB
    __hip_bfloat16* wprojT= (__hip_bfloat16*)p; p += (size_t)HH * HH * 2;        //  2MB
    __hip_bfloat16* wfc1T = (__hip_bfloat16*)p; p += (size_t)FFN_ * HH * 2;      //  8MB
    __hip_bfloat16* wfc2T = (__hip_bfloat16*)p; p += (size_t)HH * FFN_ * 2;      //  8MB

    hipMemcpyAsync(x, hidden, (size_t)BS * HH * sizeof(float),
                   hipMemcpyDeviceToDevice, stream);

    for (int lyr = 0; lyr < LYRS; ++lyr) {
        // weight transposes (fp32 -> bf16 [N,K])
        transpose_cast<<<dim3(3 * HH / 32, HH / 32), 256, 0, stream>>>(
            Wqkv + (size_t)lyr * HH * 3 * HH, wqkvT, HH, 3 * HH);
        transpose_cast<<<dim3(HH / 32, HH / 32), 256, 0, stream>>>(
            Wproj + (size_t)lyr * HH * HH, wprojT, HH, HH);
        transpose_cast<<<dim3(FFN_ / 32, HH / 32), 256, 0, stream>>>(
            Wfc1 + (size_t)lyr * HH * FFN_, wfc1T, HH, FFN_);
        transpose_cast<<<dim3(HH / 32, FFN_ / 32), 256, 0, stream>>>(
            Wfc2 + (size_t)lyr * FFN_ * HH, wfc2T, FFN_, HH);

        // h = LN1(x)  (bf16)
        ln_k<__hip_bfloat16><<<BS, 256, 0, stream>>>(
            x, ln1_g + lyr * HH, ln1_b + lyr * HH, hbuf);
        // qkv = h @ Wqkv  (bf16 out)
        gemm_bf16<false, false, __hip_bfloat16>
            <<<dim3(3 * HH / 128, BS / 128), 256, 0, stream>>>(
            hbuf, wqkvT, nullptr, qkvb, BS, 3 * HH, HH);
        // attention (bf16 -> bf16)
        attn_fa2<<<dim3(SS / 64, NHD, BB), 256, 0, stream>>>(qkvb, attnb);
        // x = x + attn @ Wproj  (fp32 out)
        gemm_bf16<false, true, float>
            <<<dim3(HH / 128, BS / 128), 256, 0, stream>>>(
            attnb, wprojT, x, x, BS, HH, HH);
        // h = LN2(x)  (bf16)
        ln_k<__hip_bfloat16><<<BS, 256, 0, stream>>>(
            x, ln2_g + lyr * HH, ln2_b + lyr * HH, hbuf);
        // ffn = gelu(h @ Wfc1)  (bf16 out)
        gemm_bf16<true, false, __hip_bfloat16>
            <<<dim3(FFN_ / 128, BS / 128), 256, 0, stream>>>(
            hbuf, wfc1T, nullptr, ffnb, BS, FFN_, HH);
        // x = x + ffn @ Wfc2  (fp32 out)
        gemm_bf16<false, true, float>
            <<<dim3(HH / 128, BS / 128), 256, 0, stream>>>(
            ffnb, wfc2T, x, x, BS, HH, FFN_);
    }
    // final LN (fp32 out, in-place on d_out)
    ln_k<float><<<BS, 256, 0, stream>>>(x, lnf_g, lnf_b, x);
}

// Round 4
// 1551.142 us; speedup vs baseline: 17.1818x; 2.4759x over previous
//
#include <hip/hip_runtime.h>
#include <hip/hip_bf16.h>
#include <math.h>

// Problem constants
#define LYRS 4
#define BB   2
#define SS   2048
#define HH   1024
#define NHD  16
#define HDD  64
#define FFN_ 4096
#define BS   (BB*SS)          // 4096 rows
#define EPS_ 1e-5f

typedef __attribute__((ext_vector_type(8))) __bf16 bf16x8;
typedef __attribute__((ext_vector_type(4))) __bf16 bf16x4;
typedef __attribute__((ext_vector_type(4))) float f32x4;
typedef __attribute__((address_space(1))) void* gas_t;
typedef __attribute__((address_space(3))) void* las_t;

__device__ inline void async16(void* lds, const void* g) {
    __builtin_amdgcn_global_load_lds((gas_t)g, (las_t)lds, 16, 0, 0);
}

__device__ inline void storev(float* p, float v) { *p = v; }
__device__ inline void storev(__hip_bfloat16* p, float v) { *p = __float2bfloat16(v); }

// ---------------- LayerNorm: one block (256 thr) per row of H=1024 ----------
template <typename OutT>
__global__ void ln_k(const float* __restrict__ x, const float* __restrict__ g,
                     const float* __restrict__ b, OutT* __restrict__ y) {
    const int row = blockIdx.x;
    const int tid = threadIdx.x;           // 256
    const float* xr = x + (size_t)row * HH;

    float v[4];
    float s = 0.f, s2 = 0.f;
#pragma unroll
    for (int i = 0; i < 4; ++i) {
        v[i] = xr[tid + i * 256];
        s  += v[i];
        s2 += v[i] * v[i];
    }
#pragma unroll
    for (int o = 1; o < 64; o <<= 1) {
        s  += __shfl_xor(s,  o);
        s2 += __shfl_xor(s2, o);
    }
    __shared__ float sh[8];
    const int wave = tid >> 6, lane = tid & 63;
    if (lane == 0) { sh[wave] = s; sh[4 + wave] = s2; }
    __syncthreads();
    if (tid == 0) {
        float ts  = sh[0] + sh[1] + sh[2] + sh[3];
        float ts2 = sh[4] + sh[5] + sh[6] + sh[7];
        float mu  = ts * (1.f / HH);
        sh[0] = mu;
        sh[1] = ts2 * (1.f / HH) - mu * mu;   // var
    }
    __syncthreads();
    const float mu   = sh[0];
    const float rstd = rsqrtf(sh[1] + EPS_);
#pragma unroll
    for (int i = 0; i < 4; ++i) {
        int c = tid + i * 256;
        storev(&y[(size_t)row * HH + c], (v[i] - mu) * rstd * g[c] + b[c]);
    }
}

// ---------------- transpose + cast: W[K,N] f32 -> WT[N,K] bf16 --------------
__global__ __launch_bounds__(256) void transpose_cast(const float* __restrict__ W,
                                                      __hip_bfloat16* __restrict__ WT,
                                                      int K, int N) {
    __shared__ float t[32][33];
    const int n0 = blockIdx.x * 32, k0 = blockIdx.y * 32;
    const int tx = threadIdx.x & 31, ty8 = threadIdx.x >> 5;   // ty8: 0..7
#pragma unroll
    for (int i = 0; i < 4; ++i) {
        int k = ty8 + i * 8;
        t[k][tx] = W[(size_t)(k0 + k) * N + n0 + tx];
    }
    __syncthreads();
#pragma unroll
    for (int i = 0; i < 4; ++i) {
        int n = ty8 + i * 8;
        WT[(size_t)(n0 + n) * K + k0 + tx] = __float2bfloat16(t[tx][n]);
    }
}

// ---------------- bf16 MFMA GEMM: C = A[M,K] @ BT[N,K]^T (+R)(gelu?) --------
template <bool GELU, bool RES, typename OutT>
__global__ __launch_bounds__(256) void gemm_bf16(
    const __hip_bfloat16* __restrict__ A,    // [M,K] row-major
    const __hip_bfloat16* __restrict__ BT,   // [N,K] row-major (= B^T)
    const float* __restrict__ R,             // residual [M,N] fp32 (or null)
    OutT* __restrict__ C,                    // [M,N]
    int M, int N, int K)
{
    __shared__ unsigned short As[128 * 32];
    __shared__ unsigned short Bs[128 * 32];

    const int tid  = threadIdx.x;
    const int lane = tid & 63;
    const int wv   = tid >> 6;               // 0..3
    const int wy   = wv >> 1, wx = wv & 1;   // 2x2 wave grid (64x64 each)
    const int row0 = blockIdx.y * 128;
    const int col0 = blockIdx.x * 128;
    const int lm   = lane & 15;
    const int kq   = lane >> 4;

    const unsigned short* Ag = (const unsigned short*)A;
    const unsigned short* Bg = (const unsigned short*)BT;

    f32x4 acc[4][4] = {};

    for (int k0 = 0; k0 < K; k0 += 32) {
        __syncthreads();
#pragma unroll
        for (int it = 0; it < 2; ++it) {
            int li = it * 256 + tid;         // 0..511, 16B each
            int r = li >> 2, c = (li & 3) << 3;
            async16(&As[li * 8], &Ag[(size_t)(row0 + r) * K + k0 + c]);
            async16(&Bs[li * 8], &Bg[(size_t)(col0 + r) * K + k0 + c]);
        }
        __syncthreads();

        bf16x8 af[4], bfr[4];
#pragma unroll
        for (int i = 0; i < 4; ++i)
            af[i] = *(const bf16x8*)&As[(wy * 64 + i * 16 + lm) * 32 + kq * 8];
#pragma unroll
        for (int j = 0; j < 4; ++j)
            bfr[j] = *(const bf16x8*)&Bs[(wx * 64 + j * 16 + lm) * 32 + kq * 8];
#pragma unroll
        for (int i = 0; i < 4; ++i)
#pragma unroll
            for (int j = 0; j < 4; ++j)
                acc[i][j] = __builtin_amdgcn_mfma_f32_16x16x32_bf16(
                    af[i], bfr[j], acc[i][j], 0, 0, 0);
    }

#pragma unroll
    for (int i = 0; i < 4; ++i) {
#pragma unroll
        for (int j = 0; j < 4; ++j) {
            int gc = col0 + wx * 64 + j * 16 + lm;
#pragma unroll
            for (int r = 0; r < 4; ++r) {
                int gr = row0 + wy * 64 + i * 16 + kq * 4 + r;
                float v = acc[i][j][r];
                if (RES)  v += R[(size_t)gr * N + gc];
                if (GELU) v = 0.5f * v * (1.0f + erff(v * 0.70710678118654752f));
                storev(&C[(size_t)gr * N + gc], v);
            }
        }
    }
}

// ---------------- MFMA causal flash attention ------------------------------
// Block = 128 queries x 1 head, 256 thr (4 waves x 2 slabs of 16 q).
// S^T = K·Q^T so softmax reduces over MFMA rows (keys): 2 shuffles, per-lane
// m/l/alpha. P^T round-trips LDS as Ps[q][key]; PV as O^T = V^T·P^T.
// qkv layout [B,S,3,NH,HD], row stride 3*H.
__global__ __launch_bounds__(256) void attn_fa3(const __bf16* __restrict__ qkv,
                                                __bf16* __restrict__ out) {
    __shared__ __bf16 Ks[64 * 72];          // K[key][d], stride 72
    __shared__ __bf16 Vt[64 * 72];          // V^T[d][key], stride 72
    __shared__ __bf16 Ps[4][2][16 * 72];    // per wave/slab: P[q][key]

    const int tid  = threadIdx.x;
    const int lane = tid & 63;
    const int w    = tid >> 6;              // wave 0..3
    const int lm   = lane & 15;
    const int kq   = lane >> 4;

    // grid decode: 512 blocks; pair {x, x+256} -> (qt, 15-qt) for balance
    const int x  = blockIdx.x;
    const int bh = x & 31;
    const int h  = bh & 15;
    const int b  = bh >> 4;
    const int a  = (x >> 5) & 7;
    const int qt = (x & 256) ? (15 - a) : a;
    const int q0 = qt * 128;

    const size_t rs   = 3 * HH;
    const size_t base = (size_t)b * SS * rs + (size_t)h * HDD;

    // Q B-frags [slab][khalf], pre-scaled by HD^-0.5 (0.125, exact in bf16)
    bf16x8 qf[2][2];
#pragma unroll
    for (int s = 0; s < 2; ++s)
#pragma unroll
        for (int kh = 0; kh < 2; ++kh) {
            bf16x8 t = *(const bf16x8*)&qkv[base +
                (size_t)(q0 + w * 32 + s * 16 + lm) * rs + kh * 32 + kq * 8];
#pragma unroll
            for (int j = 0; j < 8; ++j) t[j] = (__bf16)((float)t[j] * 0.125f);
            qf[s][kh] = t;
        }

    f32x4 ot[2][4] = {};                    // O^T acc [slab][dtile]
    float m_i[2] = {-INFINITY, -INFINITY};
    float l_i[2] = {0.f, 0.f};

    const int qmax_w = q0 + w * 32 + 31;
    const int ktmax  = (q0 + 127) >> 6;     // 2qt+1

    for (int kt = 0; kt <= ktmax; ++kt) {
        const int k0 = kt << 6;
        __syncthreads();                    // prior tile reads complete
        // stage K tile: [key][d] row-major, b128 writes
#pragma unroll
        for (int it = 0; it < 2; ++it) {
            int li  = it * 256 + tid;
            int row = li >> 3, c = (li & 7) << 3;
            *(bf16x8*)&Ks[row * 72 + c] =
                *(const bf16x8*)&qkv[base + (size_t)(k0 + row) * rs + HH + c];
        }
        // stage V^T: read V rows (strided across lanes), scalar transpose write
#pragma unroll
        for (int it = 0; it < 2; ++it) {
            int li  = it * 256 + tid;
            int key = li & 63, cb = (li >> 6) << 3;
            bf16x8 v = *(const bf16x8*)&qkv[base + (size_t)(k0 + key) * rs + 2 * HH + cb];
#pragma unroll
            for (int j = 0; j < 8; ++j) Vt[(cb + j) * 72 + key] = v[j];
        }
        __syncthreads();

        if (k0 > qmax_w) continue;          // wave-uniform skip (barriers done)

#pragma unroll
        for (int s = 0; s < 2; ++s) {
            // S^T = K·Q^T : 4 key-mtiles x 2 k-halves
            f32x4 st[4] = {};
#pragma unroll
            for (int kh = 0; kh < 2; ++kh)
#pragma unroll
                for (int m = 0; m < 4; ++m) {
                    bf16x8 kf = *(const bf16x8*)&Ks[(m * 16 + lm) * 72 + kh * 32 + kq * 8];
                    st[m] = __builtin_amdgcn_mfma_f32_16x16x32_bf16(
                        kf, qf[s][kh], st[m], 0, 0, 0);
                }

            const int qg = q0 + w * 32 + s * 16 + lm;
            if (k0 + 63 > q0 + w * 32 + s * 16) {      // partial tile: mask
#pragma unroll
                for (int m = 0; m < 4; ++m) {
                    int keyb = k0 + m * 16 + kq * 4;
#pragma unroll
                    for (int r = 0; r < 4; ++r)
                        if (keyb + r > qg) st[m][r] = -INFINITY;
                }
            }

            // online softmax over keys (rows): local 16 + 2 shuffles
            float mloc = -INFINITY;
#pragma unroll
            for (int m = 0; m < 4; ++m)
#pragma unroll
                for (int r = 0; r < 4; ++r) mloc = fmaxf(mloc, st[m][r]);
            mloc = fmaxf(mloc, __shfl_xor(mloc, 16));
            mloc = fmaxf(mloc, __shfl_xor(mloc, 32));
            float mn    = fmaxf(m_i[s], mloc);
            float alpha = __expf(m_i[s] - mn);
            m_i[s] = mn;

            float sum = 0.f;
#pragma unroll
            for (int m = 0; m < 4; ++m) {
                bf16x4 pb;
#pragma unroll
                for (int r = 0; r < 4; ++r) {
                    float p = __expf(st[m][r] - mn);
                    sum += p;
                    pb[r] = (__bf16)p;
                }
                *(bf16x4*)&Ps[w][s][lm * 72 + m * 16 + kq * 4] = pb;   // 8B packed
            }
            sum += __shfl_xor(sum, 16);
            sum += __shfl_xor(sum, 32);
            l_i[s] = l_i[s] * alpha + sum;

#pragma unroll
            for (int dt = 0; dt < 4; ++dt) ot[s][dt] *= alpha;

            // O^T += V^T · P^T : A = Vt frags, B = Ps frags
#pragma unroll
            for (int kh = 0; kh < 2; ++kh) {
                bf16x8 pf = *(const bf16x8*)&Ps[w][s][lm * 72 + kh * 32 + kq * 8];
#pragma unroll
                for (int dt = 0; dt < 4; ++dt) {
                    bf16x8 vf = *(const bf16x8*)&Vt[(dt * 16 + lm) * 72 + kh * 32 + kq * 8];
                    ot[s][dt] = __builtin_amdgcn_mfma_f32_16x16x32_bf16(
                        vf, pf, ot[s][dt], 0, 0, 0);
                }
            }
        }
    }

    // epilogue: O[q][d] = O^T[d][q] / l ; packed 8B stores
#pragma unroll
    for (int s = 0; s < 2; ++s) {
        float inv = 1.f / l_i[s];
        int qg = q0 + w * 32 + s * 16 + lm;
#pragma unroll
        for (int dt = 0; dt < 4; ++dt) {
            bf16x4 ob;
#pragma unroll
            for (int r = 0; r < 4; ++r) ob[r] = (__bf16)(ot[s][dt][r] * inv);
            *(bf16x4*)&out[(size_t)(b * SS + qg) * HH + h * HDD + dt * 16 + kq * 4] = ob;
        }
    }
}

// ---------------------------------------------------------------------------
extern "C" void kernel_launch(void* const* d_in, const int* in_sizes, int n_in,
                              void* d_out, int out_size, void* d_ws, size_t ws_size,
                              hipStream_t stream) {
    const float* hidden = (const float*)d_in[0];
    const float* ln1_g  = (const float*)d_in[1];
    const float* ln1_b  = (const float*)d_in[2];
    const float* Wqkv   = (const float*)d_in[3];
    const float* Wproj  = (const float*)d_in[4];
    const float* ln2_g  = (const float*)d_in[5];
    const float* ln2_b  = (const float*)d_in[6];
    const float* Wfc1   = (const float*)d_in[7];
    const float* Wfc2   = (const float*)d_in[8];
    const float* lnf_g  = (const float*)d_in[9];
    const float* lnf_b  = (const float*)d_in[10];

    float* x = (float*)d_out;              // residual stream (fp32) in d_out

    char* p = (char*)d_ws;
    __hip_bfloat16* hbuf  = (__hip_bfloat16*)p; p += (size_t)BS * HH * 2;
    __hip_bfloat16* qkvb  = (__hip_bfloat16*)p; p += (size_t)BS * 3 * HH * 2;
    __hip_bfloat16* attnb = (__hip_bfloat16*)p; p += (size_t)BS * HH * 2;
    __hip_bfloat16* ffnb  = (__hip_bfloat16*)p; p += (size_t)BS * FFN_ * 2;
    __hip_bfloat16* wqkvT = (__hip_bfloat16*)p; p += (size_t)3 * HH * HH * 2;
    __hip_bfloat16* wprojT= (__hip_bfloat16*)p; p += (size_t)HH * HH * 2;
    __hip_bfloat16* wfc1T = (__hip_bfloat16*)p; p += (size_t)FFN_ * HH * 2;
    __hip_bfloat16* wfc2T = (__hip_bfloat16*)p; p += (size_t)HH * FFN_ * 2;

    hipMemcpyAsync(x, hidden, (size_t)BS * HH * sizeof(float),
                   hipMemcpyDeviceToDevice, stream);

    for (int lyr = 0; lyr < LYRS; ++lyr) {
        transpose_cast<<<dim3(3 * HH / 32, HH / 32), 256, 0, stream>>>(
            Wqkv + (size_t)lyr * HH * 3 * HH, wqkvT, HH, 3 * HH);
        transpose_cast<<<dim3(HH / 32, HH / 32), 256, 0, stream>>>(
            Wproj + (size_t)lyr * HH * HH, wprojT, HH, HH);
        transpose_cast<<<dim3(FFN_ / 32, HH / 32), 256, 0, stream>>>(
            Wfc1 + (size_t)lyr * HH * FFN_, wfc1T, HH, FFN_);
        transpose_cast<<<dim3(HH / 32, FFN_ / 32), 256, 0, stream>>>(
            Wfc2 + (size_t)lyr * FFN_ * HH, wfc2T, FFN_, HH);

        ln_k<__hip_bfloat16><<<BS, 256, 0, stream>>>(
            x, ln1_g + lyr * HH, ln1_b + lyr * HH, hbuf);
        gemm_bf16<false, false, __hip_bfloat16>
            <<<dim3(3 * HH / 128, BS / 128), 256, 0, stream>>>(
            hbuf, wqkvT, nullptr, qkvb, BS, 3 * HH, HH);
        attn_fa3<<<512, 256, 0, stream>>>((const __bf16*)qkvb, (__bf16*)attnb);
        gemm_bf16<false, true, float>
            <<<dim3(HH / 128, BS / 128), 256, 0, stream>>>(
            attnb, wprojT, x, x, BS, HH, HH);
        ln_k<__hip_bfloat16><<<BS, 256, 0, stream>>>(
            x, ln2_g + lyr * HH, ln2_b + lyr * HH, hbuf);
        gemm_bf16<true, false, __hip_bfloat16>
            <<<dim3(FFN_ / 128, BS / 128), 256, 0, stream>>>(
            hbuf, wfc1T, nullptr, ffnb, BS, FFN_, HH);
        gemm_bf16<false, true, float>
            <<<dim3(HH / 128, BS / 128), 256, 0, stream>>>(
            ffnb, wfc2T, x, x, BS, HH, FFN_);
    }
    ln_k<float><<<BS, 256, 0, stream>>>(x, lnf_g, lnf_b, x);
}

// Round 5
// 1406.424 us; speedup vs baseline: 18.9498x; 1.1029x over previous
//
#include <hip/hip_runtime.h>
#include <hip/hip_bf16.h>
#include <math.h>

// Problem constants
#define LYRS 4
#define BB   2
#define SS   2048
#define HH   1024
#define NHD  16
#define HDD  64
#define FFN_ 4096
#define BS   (BB*SS)          // 4096 rows
#define EPS_ 1e-5f

typedef __attribute__((ext_vector_type(8))) __bf16 bf16x8;
typedef __attribute__((ext_vector_type(4))) __bf16 bf16x4;
typedef __attribute__((ext_vector_type(4))) float f32x4;
typedef __attribute__((address_space(1))) void* gas_t;
typedef __attribute__((address_space(3))) void* las_t;

__device__ inline void async16(void* lds, const void* g) {
    __builtin_amdgcn_global_load_lds((gas_t)g, (las_t)lds, 16, 0, 0);
}

__device__ inline void storev(float* p, float v) { *p = v; }
__device__ inline void storev(__hip_bfloat16* p, float v) { *p = __float2bfloat16(v); }

// ---------------- LayerNorm: one block (256 thr) per row of H=1024 ----------
template <typename OutT>
__global__ void ln_k(const float* __restrict__ x, const float* __restrict__ g,
                     const float* __restrict__ b, OutT* __restrict__ y) {
    const int row = blockIdx.x;
    const int tid = threadIdx.x;           // 256
    const float* xr = x + (size_t)row * HH;

    float v[4];
    float s = 0.f, s2 = 0.f;
#pragma unroll
    for (int i = 0; i < 4; ++i) {
        v[i] = xr[tid + i * 256];
        s  += v[i];
        s2 += v[i] * v[i];
    }
#pragma unroll
    for (int o = 1; o < 64; o <<= 1) {
        s  += __shfl_xor(s,  o);
        s2 += __shfl_xor(s2, o);
    }
    __shared__ float sh[8];
    const int wave = tid >> 6, lane = tid & 63;
    if (lane == 0) { sh[wave] = s; sh[4 + wave] = s2; }
    __syncthreads();
    if (tid == 0) {
        float ts  = sh[0] + sh[1] + sh[2] + sh[3];
        float ts2 = sh[4] + sh[5] + sh[6] + sh[7];
        float mu  = ts * (1.f / HH);
        sh[0] = mu;
        sh[1] = ts2 * (1.f / HH) - mu * mu;   // var
    }
    __syncthreads();
    const float mu   = sh[0];
    const float rstd = rsqrtf(sh[1] + EPS_);
#pragma unroll
    for (int i = 0; i < 4; ++i) {
        int c = tid + i * 256;
        storev(&y[(size_t)row * HH + c], (v[i] - mu) * rstd * g[c] + b[c]);
    }
}

// ---------------- transpose + cast: W[K,N] f32 -> WT[N,K] bf16 --------------
__global__ __launch_bounds__(256) void transpose_cast(const float* __restrict__ W,
                                                      __hip_bfloat16* __restrict__ WT,
                                                      int K, int N) {
    __shared__ float t[32][33];
    const int n0 = blockIdx.x * 32, k0 = blockIdx.y * 32;
    const int tx = threadIdx.x & 31, ty8 = threadIdx.x >> 5;   // ty8: 0..7
#pragma unroll
    for (int i = 0; i < 4; ++i) {
        int k = ty8 + i * 8;
        t[k][tx] = W[(size_t)(k0 + k) * N + n0 + tx];
    }
    __syncthreads();
#pragma unroll
    for (int i = 0; i < 4; ++i) {
        int n = ty8 + i * 8;
        WT[(size_t)(n0 + n) * K + k0 + tx] = __float2bfloat16(t[tx][n]);
    }
}

// ---------------- bf16 MFMA GEMM: C = A[M,K] @ BT[N,K]^T (+R)(gelu?) --------
// 1D grid, row = bid % (M/128) so all col-blocks of one A-row-slab share
// bid%8 -> same XCD -> A-slab fetched once per XCD L2.
template <bool GELU, bool RES, typename OutT>
__global__ __launch_bounds__(256) void gemm_bf16(
    const __hip_bfloat16* __restrict__ A,    // [M,K] row-major
    const __hip_bfloat16* __restrict__ BT,   // [N,K] row-major (= B^T)
    const float* __restrict__ R,             // residual [M,N] fp32 (or null)
    OutT* __restrict__ C,                    // [M,N]
    int M, int N, int K)
{
    __shared__ unsigned short As[128 * 32];
    __shared__ unsigned short Bs[128 * 32];

    const int tid  = threadIdx.x;
    const int lane = tid & 63;
    const int wv   = tid >> 6;               // 0..3
    const int wy   = wv >> 1, wx = wv & 1;   // 2x2 wave grid (64x64 each)
    const int nby  = M >> 7;                 // 32
    const int by   = blockIdx.x % nby;
    const int bx   = blockIdx.x / nby;
    const int row0 = by * 128;
    const int col0 = bx * 128;
    const int lm   = lane & 15;
    const int kq   = lane >> 4;

    const unsigned short* Ag = (const unsigned short*)A;
    const unsigned short* Bg = (const unsigned short*)BT;

    f32x4 acc[4][4] = {};

    for (int k0 = 0; k0 < K; k0 += 32) {
        __syncthreads();
#pragma unroll
        for (int it = 0; it < 2; ++it) {
            int li = it * 256 + tid;         // 0..511, 16B each
            int r = li >> 2, c = (li & 3) << 3;
            async16(&As[li * 8], &Ag[(size_t)(row0 + r) * K + k0 + c]);
            async16(&Bs[li * 8], &Bg[(size_t)(col0 + r) * K + k0 + c]);
        }
        __syncthreads();

        bf16x8 af[4], bfr[4];
#pragma unroll
        for (int i = 0; i < 4; ++i)
            af[i] = *(const bf16x8*)&As[(wy * 64 + i * 16 + lm) * 32 + kq * 8];
#pragma unroll
        for (int j = 0; j < 4; ++j)
            bfr[j] = *(const bf16x8*)&Bs[(wx * 64 + j * 16 + lm) * 32 + kq * 8];
#pragma unroll
        for (int i = 0; i < 4; ++i)
#pragma unroll
            for (int j = 0; j < 4; ++j)
                acc[i][j] = __builtin_amdgcn_mfma_f32_16x16x32_bf16(
                    af[i], bfr[j], acc[i][j], 0, 0, 0);
    }

#pragma unroll
    for (int i = 0; i < 4; ++i) {
#pragma unroll
        for (int j = 0; j < 4; ++j) {
            int gc = col0 + wx * 64 + j * 16 + lm;
#pragma unroll
            for (int r = 0; r < 4; ++r) {
                int gr = row0 + wy * 64 + i * 16 + kq * 4 + r;
                float v = acc[i][j][r];
                if (RES)  v += R[(size_t)gr * N + gc];
                if (GELU) v = 0.5f * v * (1.0f + erff(v * 0.70710678118654752f));
                storev(&C[(size_t)gr * N + gc], v);
            }
        }
    }
}

// ---------------- MFMA causal flash attention (double-buffered) -------------
// Block = 128 queries x 1 head, 256 thr (4 waves x 2 slabs of 16 q).
// S^T = K·Q^T; softmax over MFMA rows (keys). P^T via LDS; O^T = V^T·P^T.
// K/V staging ping-pongs between 2 LDS buffers; tile t+1's global loads are
// issued before computing tile t (latency hidden); one barrier per tile.
__global__ __launch_bounds__(256) void attn_fa3(const __bf16* __restrict__ qkv,
                                                __bf16* __restrict__ out) {
    __shared__ __bf16 Ks[2][64 * 72];       // K[key][d], stride 72
    __shared__ __bf16 Vt[2][64 * 72];       // V^T[d][key], stride 72
    __shared__ __bf16 Ps[4][2][16 * 72];    // per wave/slab: P[q][key]

    const int tid  = threadIdx.x;
    const int lane = tid & 63;
    const int w    = tid >> 6;              // wave 0..3
    const int lm   = lane & 15;
    const int kq   = lane >> 4;

    // grid decode: 512 blocks; pair {x, x+256} -> (qt, 15-qt) for balance
    const int x  = blockIdx.x;
    const int bh = x & 31;
    const int h  = bh & 15;
    const int b  = bh >> 4;
    const int a  = (x >> 5) & 7;
    const int qt = (x & 256) ? (15 - a) : a;
    const int q0 = qt * 128;

    const size_t rs   = 3 * HH;
    const size_t base = (size_t)b * SS * rs + (size_t)h * HDD;

    // staging address components (fixed per thread)
    const int krow0 = tid >> 3,        kc0 = (tid & 7) << 3;          // it=0
    const int krow1 = (256 + tid) >> 3, kc1 = ((256 + tid) & 7) << 3; // it=1
    const int vkey  = tid & 63;
    const int vcb0  = (tid >> 6) << 3, vcb1 = ((256 + tid) >> 6) << 3;

    // Q B-frags [slab][khalf], pre-scaled by HD^-0.5 (0.125, exact in bf16)
    bf16x8 qf[2][2];
#pragma unroll
    for (int s = 0; s < 2; ++s)
#pragma unroll
        for (int kh = 0; kh < 2; ++kh) {
            bf16x8 t = *(const bf16x8*)&qkv[base +
                (size_t)(q0 + w * 32 + s * 16 + lm) * rs + kh * 32 + kq * 8];
#pragma unroll
            for (int j = 0; j < 8; ++j) t[j] = (__bf16)((float)t[j] * 0.125f);
            qf[s][kh] = t;
        }

    f32x4 ot[2][4] = {};                    // O^T acc [slab][dtile]
    float m_i[2] = {-INFINITY, -INFINITY};
    float l_i[2] = {0.f, 0.f};

    const int qmax_w = q0 + w * 32 + 31;
    const int ktmax  = (q0 + 127) >> 6;     // 2qt+1

    bf16x8 kr0, kr1, vr0, vr1;
    // prologue: load tile 0
    {
        const int k0 = 0;
        kr0 = *(const bf16x8*)&qkv[base + (size_t)(k0 + krow0) * rs + HH + kc0];
        kr1 = *(const bf16x8*)&qkv[base + (size_t)(k0 + krow1) * rs + HH + kc1];
        vr0 = *(const bf16x8*)&qkv[base + (size_t)(k0 + vkey) * rs + 2 * HH + vcb0];
        vr1 = *(const bf16x8*)&qkv[base + (size_t)(k0 + vkey) * rs + 2 * HH + vcb1];
        *(bf16x8*)&Ks[0][krow0 * 72 + kc0] = kr0;
        *(bf16x8*)&Ks[0][krow1 * 72 + kc1] = kr1;
#pragma unroll
        for (int j = 0; j < 8; ++j) Vt[0][(vcb0 + j) * 72 + vkey] = vr0[j];
#pragma unroll
        for (int j = 0; j < 8; ++j) Vt[0][(vcb1 + j) * 72 + vkey] = vr1[j];
    }
    __syncthreads();

    for (int kt = 0; kt <= ktmax; ++kt) {
        const int k0  = kt << 6;
        const int buf = kt & 1;

        // issue next tile's global loads (latency overlapped with compute)
        if (kt < ktmax) {
            const int kn = k0 + 64;
            kr0 = *(const bf16x8*)&qkv[base + (size_t)(kn + krow0) * rs + HH + kc0];
            kr1 = *(const bf16x8*)&qkv[base + (size_t)(kn + krow1) * rs + HH + kc1];
            vr0 = *(const bf16x8*)&qkv[base + (size_t)(kn + vkey) * rs + 2 * HH + vcb0];
            vr1 = *(const bf16x8*)&qkv[base + (size_t)(kn + vkey) * rs + 2 * HH + vcb1];
        }

        if (k0 <= qmax_w) {                 // wave-uniform causal skip
#pragma unroll
            for (int s = 0; s < 2; ++s) {
                // S^T = K·Q^T : 4 key-mtiles x 2 k-halves
                f32x4 st[4] = {};
#pragma unroll
                for (int kh = 0; kh < 2; ++kh)
#pragma unroll
                    for (int m = 0; m < 4; ++m) {
                        bf16x8 kf = *(const bf16x8*)&Ks[buf][(m * 16 + lm) * 72 + kh * 32 + kq * 8];
                        st[m] = __builtin_amdgcn_mfma_f32_16x16x32_bf16(
                            kf, qf[s][kh], st[m], 0, 0, 0);
                    }

                const int qg = q0 + w * 32 + s * 16 + lm;
                if (k0 + 63 > q0 + w * 32 + s * 16) {      // partial tile: mask
#pragma unroll
                    for (int m = 0; m < 4; ++m) {
                        int keyb = k0 + m * 16 + kq * 4;
#pragma unroll
                        for (int r = 0; r < 4; ++r)
                            if (keyb + r > qg) st[m][r] = -INFINITY;
                    }
                }

                // online softmax over keys (rows): local 16 + 2 shuffles
                float mloc = -INFINITY;
#pragma unroll
                for (int m = 0; m < 4; ++m)
#pragma unroll
                    for (int r = 0; r < 4; ++r) mloc = fmaxf(mloc, st[m][r]);
                mloc = fmaxf(mloc, __shfl_xor(mloc, 16));
                mloc = fmaxf(mloc, __shfl_xor(mloc, 32));
                float mn    = fmaxf(m_i[s], mloc);
                float alpha = __expf(m_i[s] - mn);
                m_i[s] = mn;

                float sum = 0.f;
#pragma unroll
                for (int m = 0; m < 4; ++m) {
                    bf16x4 pb;
#pragma unroll
                    for (int r = 0; r < 4; ++r) {
                        float p = __expf(st[m][r] - mn);
                        sum += p;
                        pb[r] = (__bf16)p;
                    }
                    *(bf16x4*)&Ps[w][s][lm * 72 + m * 16 + kq * 4] = pb;   // 8B packed
                }
                sum += __shfl_xor(sum, 16);
                sum += __shfl_xor(sum, 32);
                l_i[s] = l_i[s] * alpha + sum;

#pragma unroll
                for (int dt = 0; dt < 4; ++dt) ot[s][dt] *= alpha;

                // O^T += V^T · P^T : A = Vt frags, B = Ps frags
#pragma unroll
                for (int kh = 0; kh < 2; ++kh) {
                    bf16x8 pf = *(const bf16x8*)&Ps[w][s][lm * 72 + kh * 32 + kq * 8];
#pragma unroll
                    for (int dt = 0; dt < 4; ++dt) {
                        bf16x8 vf = *(const bf16x8*)&Vt[buf][(dt * 16 + lm) * 72 + kh * 32 + kq * 8];
                        ot[s][dt] = __builtin_amdgcn_mfma_f32_16x16x32_bf16(
                            vf, pf, ot[s][dt], 0, 0, 0);
                    }
                }
            }
        }

        // store next tile into the other buffer, then one barrier
        if (kt < ktmax) {
            const int nb = buf ^ 1;
            *(bf16x8*)&Ks[nb][krow0 * 72 + kc0] = kr0;
            *(bf16x8*)&Ks[nb][krow1 * 72 + kc1] = kr1;
#pragma unroll
            for (int j = 0; j < 8; ++j) Vt[nb][(vcb0 + j) * 72 + vkey] = vr0[j];
#pragma unroll
            for (int j = 0; j < 8; ++j) Vt[nb][(vcb1 + j) * 72 + vkey] = vr1[j];
            __syncthreads();
        }
    }

    // epilogue: O[q][d] = O^T[d][q] / l ; packed 8B stores
#pragma unroll
    for (int s = 0; s < 2; ++s) {
        float inv = 1.f / l_i[s];
        int qg = q0 + w * 32 + s * 16 + lm;
#pragma unroll
        for (int dt = 0; dt < 4; ++dt) {
            bf16x4 ob;
#pragma unroll
            for (int r = 0; r < 4; ++r) ob[r] = (__bf16)(ot[s][dt][r] * inv);
            *(bf16x4*)&out[(size_t)(b * SS + qg) * HH + h * HDD + dt * 16 + kq * 4] = ob;
        }
    }
}

// ---------------------------------------------------------------------------
extern "C" void kernel_launch(void* const* d_in, const int* in_sizes, int n_in,
                              void* d_out, int out_size, void* d_ws, size_t ws_size,
                              hipStream_t stream) {
    const float* hidden = (const float*)d_in[0];
    const float* ln1_g  = (const float*)d_in[1];
    const float* ln1_b  = (const float*)d_in[2];
    const float* Wqkv   = (const float*)d_in[3];
    const float* Wproj  = (const float*)d_in[4];
    const float* ln2_g  = (const float*)d_in[5];
    const float* ln2_b  = (const float*)d_in[6];
    const float* Wfc1   = (const float*)d_in[7];
    const float* Wfc2   = (const float*)d_in[8];
    const float* lnf_g  = (const float*)d_in[9];
    const float* lnf_b  = (const float*)d_in[10];

    float* x = (float*)d_out;              // residual stream (fp32) in d_out

    char* p = (char*)d_ws;
    __hip_bfloat16* hbuf  = (__hip_bfloat16*)p; p += (size_t)BS * HH * 2;
    __hip_bfloat16* qkvb  = (__hip_bfloat16*)p; p += (size_t)BS * 3 * HH * 2;
    __hip_bfloat16* attnb = (__hip_bfloat16*)p; p += (size_t)BS * HH * 2;
    __hip_bfloat16* ffnb  = (__hip_bfloat16*)p; p += (size_t)BS * FFN_ * 2;
    __hip_bfloat16* wqkvT = (__hip_bfloat16*)p; p += (size_t)3 * HH * HH * 2;
    __hip_bfloat16* wprojT= (__hip_bfloat16*)p; p += (size_t)HH * HH * 2;
    __hip_bfloat16* wfc1T = (__hip_bfloat16*)p; p += (size_t)FFN_ * HH * 2;
    __hip_bfloat16* wfc2T = (__hip_bfloat16*)p; p += (size_t)HH * FFN_ * 2;

    hipMemcpyAsync(x, hidden, (size_t)BS * HH * sizeof(float),
                   hipMemcpyDeviceToDevice, stream);

    const int NBY = BS / 128;   // 32

    for (int lyr = 0; lyr < LYRS; ++lyr) {
        transpose_cast<<<dim3(3 * HH / 32, HH / 32), 256, 0, stream>>>(
            Wqkv + (size_t)lyr * HH * 3 * HH, wqkvT, HH, 3 * HH);
        transpose_cast<<<dim3(HH / 32, HH / 32), 256, 0, stream>>>(
            Wproj + (size_t)lyr * HH * HH, wprojT, HH, HH);
        transpose_cast<<<dim3(FFN_ / 32, HH / 32), 256, 0, stream>>>(
            Wfc1 + (size_t)lyr * HH * FFN_, wfc1T, HH, FFN_);
        transpose_cast<<<dim3(HH / 32, FFN_ / 32), 256, 0, stream>>>(
            Wfc2 + (size_t)lyr * FFN_ * HH, wfc2T, FFN_, HH);

        ln_k<__hip_bfloat16><<<BS, 256, 0, stream>>>(
            x, ln1_g + lyr * HH, ln1_b + lyr * HH, hbuf);
        gemm_bf16<false, false, __hip_bfloat16>
            <<<(3 * HH / 128) * NBY, 256, 0, stream>>>(
            hbuf, wqkvT, nullptr, qkvb, BS, 3 * HH, HH);
        attn_fa3<<<512, 256, 0, stream>>>((const __bf16*)qkvb, (__bf16*)attnb);
        gemm_bf16<false, true, float>
            <<<(HH / 128) * NBY, 256, 0, stream>>>(
            attnb, wprojT, x, x, BS, HH, HH);
        ln_k<__hip_bfloat16><<<BS, 256, 0, stream>>>(
            x, ln2_g + lyr * HH, ln2_b + lyr * HH, hbuf);
        gemm_bf16<true, false, __hip_bfloat16>
            <<<(FFN_ / 128) * NBY, 256, 0, stream>>>(
            hbuf, wfc1T, nullptr, ffnb, BS, FFN_, HH);
        gemm_bf16<false, true, float>
            <<<(HH / 128) * NBY, 256, 0, stream>>>(
            ffnb, wfc2T, x, x, BS, HH, FFN_);
    }
    ln_k<float><<<BS, 256, 0, stream>>>(x, lnf_g, lnf_b, x);
}